// Round 14
// baseline (221.664 us; speedup 1.0000x reference)
//
#include <hip/hip_runtime.h>
#include <math.h>

// Problem constants (from setup_inputs): B,V,C,D,H,W = 2,5,32,48,128,160
constexpr int B_ = 2;
constexpr int V_ = 5;
constexpr int C_ = 32;
constexpr int D_ = 48;
constexpr int H_ = 128;
constexpr int W_ = 160;
constexpr int HW_ = H_ * W_;               // 20480
constexpr int NVOX = B_ * D_ * HW_;        // 1,966,080
constexpr int PLANE = D_ * HW_;            // 983,040 (per-batch voxels)

typedef short short8 __attribute__((ext_vector_type(8)));
typedef float floatx4 __attribute__((ext_vector_type(4)));

// ---------------- small matrix helpers (device) ----------------

__device__ inline void combine4(const float* pm, float out[4][4]) {
    const float* E = pm;
    const float* K = pm + 16;
    for (int i = 0; i < 3; ++i)
        for (int j = 0; j < 4; ++j) {
            float a = 0.f;
            for (int k = 0; k < 3; ++k) a += K[i * 4 + k] * E[k * 4 + j];
            out[i][j] = a;
        }
    for (int j = 0; j < 4; ++j) out[3][j] = E[12 + j];
}

__device__ inline void invert4(const float A[4][4], float inv[4][4]) {
    float M[4][8];
    for (int i = 0; i < 4; ++i)
        for (int j = 0; j < 4; ++j) {
            M[i][j] = A[i][j];
            M[i][4 + j] = (i == j) ? 1.f : 0.f;
        }
    for (int col = 0; col < 4; ++col) {
        int piv = col;
        float best = fabsf(M[col][col]);
        for (int r = col + 1; r < 4; ++r) {
            float v = fabsf(M[r][col]);
            if (v > best) { best = v; piv = r; }
        }
        if (piv != col)
            for (int j = 0; j < 8; ++j) { float t = M[col][j]; M[col][j] = M[piv][j]; M[piv][j] = t; }
        float ip = 1.f / M[col][col];
        for (int j = 0; j < 8; ++j) M[col][j] *= ip;
        for (int r = 0; r < 4; ++r) {
            if (r == col) continue;
            float f = M[r][col];
            for (int j = 0; j < 8; ++j) M[r][j] -= f * M[col][j];
        }
    }
    for (int i = 0; i < 4; ++i)
        for (int j = 0; j < 4; ++j) inv[i][j] = M[i][4 + j];
}

__device__ inline unsigned bf_rne(float f) {
    unsigned u = __float_as_uint(f);
    return (u + 0x7FFFu + ((u >> 16) & 1u)) >> 16;   // RNE (values are finite)
}

__device__ inline float bflo(unsigned u) { return __uint_as_float(u << 16); }
__device__ inline float bfhi(unsigned u) { return __uint_as_float(u & 0xffff0000u); }

// setup: (a) per b,v: P = src_proj @ inv(ref_proj) -> rt[12 floats]
//        (b) prepack conv weights as bf16 MFMA A-fragments:
//            A[m=tap=lane&15 (+16i)][k=ch=(lane>>4)*8+j], taps>=27 zero-padded
__global__ void setup_kernel(const float* __restrict__ proj, const float* __restrict__ wreg,
                             float* __restrict__ rt, unsigned* __restrict__ wtb) {
    int t = threadIdx.x;
    if (t < B_) {
        int b = t;
        float ref[4][4], inv[4][4];
        combine4(proj + (size_t)((b * V_ + 0) * 2) * 16, ref);
        invert4(ref, inv);
        for (int v = 1; v < V_; ++v) {
            float src[4][4];
            combine4(proj + (size_t)((b * V_ + v) * 2) * 16, src);
            float P[3][4];
            for (int i = 0; i < 3; ++i)
                for (int j = 0; j < 4; ++j) {
                    float a = 0.f;
                    for (int k = 0; k < 4; ++k) a += src[i][k] * inv[k][j];
                    P[i][j] = a;
                }
            float* o = rt + (size_t)(b * (V_ - 1) + (v - 1)) * 12;
            o[0] = P[0][0]; o[1] = P[0][1]; o[2] = P[0][2];
            o[3] = P[1][0]; o[4] = P[1][1]; o[5] = P[1][2];
            o[6] = P[2][0]; o[7] = P[2][1]; o[8] = P[2][2];
            o[9] = P[0][3]; o[10] = P[1][3]; o[11] = P[2][3];
        }
    }
    if (t < 128) {
        int i = t >> 6;          // which mfma (taps 0-15 / 16-31)
        int lane = t & 63;
        int q = lane >> 4;
        int l = lane & 15;
        int tap = i * 16 + l;
        unsigned u[4];
#pragma unroll
        for (int jj = 0; jj < 4; ++jj) {
            int ch0 = q * 8 + 2 * jj;
            float v0 = (tap < 27) ? wreg[ch0 * 27 + tap] : 0.f;
            float v1 = (tap < 27) ? wreg[(ch0 + 1) * 27 + tap] : 0.f;
            u[jj] = bf_rne(v0) | (bf_rne(v1) << 16);
        }
        uint4* o = (uint4*)wtb;
        o[i * 64 + lane] = make_uint4(u[0], u[1], u[2], u[3]);
    }
}

// transpose features (B,V,C,H,W) f32 -> channel-last bf16 (B,V,H,W,C): 64 B/pixel
__global__ __launch_bounds__(256) void transpose_kernel(const float* __restrict__ feat,
                                                        unsigned* __restrict__ feat_cl) {
    int idx = blockIdx.x * 256 + threadIdx.x;  // over B*V*HW
    if (idx >= B_ * V_ * HW_) return;
    int pix = idx % HW_;
    int bv = idx / HW_;
    const float* src = feat + (size_t)bv * C_ * HW_ + pix;
    unsigned u[16];
#pragma unroll
    for (int j = 0; j < 16; ++j) {
        float a = src[(size_t)(2 * j) * HW_];
        float b = src[(size_t)(2 * j + 1) * HW_];
        u[j] = bf_rne(a) | (bf_rne(b) << 16);
    }
    uint4* dst = (uint4*)(feat_cl + (size_t)idx * 16);
    dst[0] = make_uint4(u[0], u[1], u[2], u[3]);
    dst[1] = make_uint4(u[4], u[5], u[6], u[7]);
    dst[2] = make_uint4(u[8], u[9], u[10], u[11]);
    dst[3] = make_uint4(u[12], u[13], u[14], u[15]);
}

// Fused homography warp + bilinear + variance + conv channel-reduction.
// Block = 256 threads = 64 pixels x 4 channel-quarter lanes; grid (320, D, B)
// so b/d/depth are wave-uniform (SGPR). bf16 channel-last features: one 16B
// load covers a corner's 8 channels. Lane cq of each quad computes view cq's
// projection; weights+offsets broadcast per view via quad shfl — the R13
// all-views up-front hoist regressed (124.8 -> 130.9 us, VALUBusy 77 -> 72):
// the compiler already extracts the available MLP; the hoist lengthened the
// critical path. T-dot on MFMA; 27 tap planes stored as bf16.
// T layout: [j=0..26][b][d][h][w], ushort.
__global__ __launch_bounds__(256) void warp_kernel(const unsigned char* __restrict__ fb,
                                                   const float* __restrict__ rt,
                                                   const float* __restrict__ dv,
                                                   const unsigned* __restrict__ wtb,
                                                   unsigned short* __restrict__ T) {
    const int tid = threadIdx.x;
    const int lane = tid & 63;
    const int cq = tid & 3;                   // channel quarter
    const int b = blockIdx.z;
    const int d = blockIdx.y;
    const int pixb = blockIdx.x * 64;         // block's first pixel
    const int pix = pixb + (tid >> 2);
    const int w = pix % W_;
    const int h = pix / W_;
    const float wf = (float)w, hf = (float)h;
    const float dep = dv[b * D_ + d];         // uniform -> s_load

    // A-fragments (bf16 conv weights), constant per lane
    const uint4* wp = (const uint4*)wtb;
    uint4 a0u = wp[lane];
    uint4 a1u = wp[64 + lane];

    // own view (cq): projection + bilinear weights + corner pixel indices
    float w00, w01, w10, w11;
    int pix00, pix01, pix10, pix11;
    {
        const float* m = rt + (b * (V_ - 1) + cq) * 12;
        float xp = fmaf(fmaf(m[0], wf, fmaf(m[1], hf, m[2])), dep, m[9]);
        float yp = fmaf(fmaf(m[3], wf, fmaf(m[4], hf, m[5])), dep, m[10]);
        float zp = fmaf(fmaf(m[6], wf, fmaf(m[7], hf, m[8])), dep, m[11]);
        float iz = __builtin_amdgcn_rcpf(zp);
        float ix = xp * iz, iy = yp * iz;
        float x0f = floorf(ix), y0f = floorf(iy);
        float wx1 = ix - x0f, wx0 = 1.f - wx1;
        float wy1 = iy - y0f, wy0 = 1.f - wy1;
        float x1f = x0f + 1.f, y1f = y0f + 1.f;
        bool vx0 = (x0f >= 0.f) && (x0f <= (float)(W_ - 1));
        bool vx1 = (x1f >= 0.f) && (x1f <= (float)(W_ - 1));
        bool vy0 = (y0f >= 0.f) && (y0f <= (float)(H_ - 1));
        bool vy1 = (y1f >= 0.f) && (y1f <= (float)(H_ - 1));
        int x0i = (int)fminf(fmaxf(x0f, 0.f), (float)(W_ - 1));
        int x1i = (int)fminf(fmaxf(x1f, 0.f), (float)(W_ - 1));
        int y0i = (int)fminf(fmaxf(y0f, 0.f), (float)(H_ - 1));
        int y1i = (int)fminf(fmaxf(y1f, 0.f), (float)(H_ - 1));
        w00 = wx0 * wy0 * ((vx0 && vy0) ? 1.f : 0.f);
        w01 = wx1 * wy0 * ((vx1 && vy0) ? 1.f : 0.f);
        w10 = wx0 * wy1 * ((vx0 && vy1) ? 1.f : 0.f);
        w11 = wx1 * wy1 * ((vx1 && vy1) ? 1.f : 0.f);
        pix00 = y0i * W_ + x0i;
        pix01 = y0i * W_ + x1i;
        pix10 = y1i * W_ + x0i;
        pix11 = y1i * W_ + x1i;
    }

    // ref view: own pixel, own 8 channels (bf16x8 = one 16B load)
    float s[8], q[8];
    {
        const unsigned char* rb = fb + (size_t)(b * V_) * HW_ * 64;
        uint4 r = *(const uint4*)(rb + (((unsigned)pix) << 6) + (cq << 4));
        float f0 = bflo(r.x), f1 = bfhi(r.x);
        float f2 = bflo(r.y), f3 = bfhi(r.y);
        float f4 = bflo(r.z), f5 = bfhi(r.z);
        float f6 = bflo(r.w), f7 = bfhi(r.w);
        s[0] = f0; s[1] = f1; s[2] = f2; s[3] = f3;
        s[4] = f4; s[5] = f5; s[6] = f6; s[7] = f7;
        q[0] = f0 * f0; q[1] = f1 * f1; q[2] = f2 * f2; q[3] = f3 * f3;
        q[4] = f4 * f4; q[5] = f5 * f5; q[6] = f6 * f6; q[7] = f7 * f7;
    }

#pragma unroll
    for (int v = 0; v < V_ - 1; ++v) {
        int sl = (lane & ~3) | v;             // quad-local broadcast source
        float W00 = __shfl(w00, sl), W01 = __shfl(w01, sl);
        float W10 = __shfl(w10, sl), W11 = __shfl(w11, sl);
        unsigned O00 = ((unsigned)__shfl(pix00, sl) << 6) + (cq << 4);
        unsigned O01 = ((unsigned)__shfl(pix01, sl) << 6) + (cq << 4);
        unsigned O10 = ((unsigned)__shfl(pix10, sl) << 6) + (cq << 4);
        unsigned O11 = ((unsigned)__shfl(pix11, sl) << 6) + (cq << 4);
        const unsigned char* base = fb + (size_t)(b * V_ + v + 1) * HW_ * 64;
        uint4 c0 = *(const uint4*)(base + O00);
        uint4 c1 = *(const uint4*)(base + O01);
        uint4 c2 = *(const uint4*)(base + O10);
        uint4 c3 = *(const uint4*)(base + O11);
        unsigned u0[4] = {c0.x, c0.y, c0.z, c0.w};
        unsigned u1[4] = {c1.x, c1.y, c1.z, c1.w};
        unsigned u2[4] = {c2.x, c2.y, c2.z, c2.w};
        unsigned u3[4] = {c3.x, c3.y, c3.z, c3.w};
#pragma unroll
        for (int jj = 0; jj < 4; ++jj) {
            float a0 = bflo(u0[jj]);
            float b0 = bflo(u1[jj]);
            float g0 = bflo(u2[jj]);
            float d0 = bflo(u3[jj]);
            float acc = fmaf(a0, W00, fmaf(b0, W01, fmaf(g0, W10, d0 * W11)));
            s[2 * jj] += acc;
            q[2 * jj] = fmaf(acc, acc, q[2 * jj]);
            float a1 = bfhi(u0[jj]);
            float b1 = bfhi(u1[jj]);
            float g1 = bfhi(u2[jj]);
            float d1 = bfhi(u3[jj]);
            float acc1 = fmaf(a1, W00, fmaf(b1, W01, fmaf(g1, W10, d1 * W11)));
            s[2 * jj + 1] += acc1;
            q[2 * jj + 1] = fmaf(acc1, acc1, q[2 * jj + 1]);
        }
    }

    // variance for this thread's 8 channels, packed to bf16
    const float invV = 1.0f / (float)V_;
    unsigned pk[4];
#pragma unroll
    for (int jj = 0; jj < 4; ++jj) {
        float m0 = s[2 * jj] * invV, m1 = s[2 * jj + 1] * invV;
        float v0 = fmaf(-m0, m0, q[2 * jj] * invV);
        float v1 = fmaf(-m1, m1, q[2 * jj + 1] * invV);
        pk[jj] = bf_rne(v0) | (bf_rne(v1) << 16);
    }

    // permute to B-fragment layout: target lane L gets (voxel L&15, quarter L>>4)
    // which lives in source lane (L&15)*4 + (L>>4)
    uint4 bu;
    {
        int srcl = ((lane & 15) << 2) + (lane >> 4);
        bu.x = (unsigned)__shfl((int)pk[0], srcl);
        bu.y = (unsigned)__shfl((int)pk[1], srcl);
        bu.z = (unsigned)__shfl((int)pk[2], srcl);
        bu.w = (unsigned)__shfl((int)pk[3], srcl);
    }
    short8 bfrag = __builtin_bit_cast(short8, bu);
    short8 afrag0 = __builtin_bit_cast(short8, a0u);
    short8 afrag1 = __builtin_bit_cast(short8, a1u);

    floatx4 z = {0.f, 0.f, 0.f, 0.f};
    // D[m=tap][n=voxel-in-wave]; lane L: col=L&15, rows=(L>>4)*4+r
    floatx4 t0 = __builtin_amdgcn_mfma_f32_16x16x32_bf16(afrag0, bfrag, z, 0, 0, 0);
    floatx4 t1 = __builtin_amdgcn_mfma_f32_16x16x32_bf16(afrag1, bfrag, z, 0, 0, 0);

    // store taps as bf16 straight to the 27 T planes
    const unsigned gidx = (unsigned)(b * PLANE + d * HW_ + pixb + ((tid >> 6) << 4) + (lane & 15));
    const int tq = (lane >> 4) << 2;
#pragma unroll
    for (int r = 0; r < 4; ++r) {
        T[(unsigned)((tq + r) * NVOX) + gidx] = (unsigned short)bf_rne(t0[r]);
        int tap2 = 16 + tq + r;
        if (tap2 < 27) T[(unsigned)(tap2 * NVOX) + gidx] = (unsigned short)bf_rne(t1[r]);
    }
}

// Fused cost gather + softmax/depth/conf/itg, full parallelism.
// Block = 384 threads; grid = B*HW/64 blocks (one per 64-pixel chunk).
// Phase 1 (= R12 cost structure, same 3840-wave total): thread (d, octet)
// accumulates cost for 8 consecutive w's of one depth via 3 aligned uint4
// loads + 2 predicated edge scalars per (kd,kh); result to a 12 KB LDS tile
// [48 d][64 pix]. Phase 2: thread (pixel, sixth) owns 8 d's; max/S/S2/depth/
// dif/conf combined via LDS; each thread writes its 8 itg planes.
__global__ __launch_bounds__(384) void costout_kernel(const unsigned short* __restrict__ T,
                                                      const float* __restrict__ dv,
                                                      float* __restrict__ out) {
    __shared__ float lc[D_][64];
    __shared__ float red[6][64];
    const int tid = threadIdx.x;
    const int pix0 = blockIdx.x * 64;          // global pixel base (over B*HW)

    // ---- phase 1: vectorized cost gather into LDS ----
    {
        const int o = tid & 7;                 // w-octet within the 64-pixel chunk
        const int d = tid >> 3;                // depth 0..47
        const int pg = pix0 + o * 8;           // first global pixel of octet
        const int b = pg / HW_;
        const int pp = pg - b * HW_;
        const int h = pp / W_;
        const int w0 = pp - h * W_;
        float acc[8];
#pragma unroll
        for (int i = 0; i < 8; ++i) acc[i] = 0.f;
#pragma unroll
        for (int kd = 0; kd < 3; ++kd) {
            int dd = d + kd - 1;
            if (dd < 0 || dd >= D_) continue;
#pragma unroll
            for (int kh = 0; kh < 3; ++kh) {
                int hh = h + kh - 1;
                if (hh < 0 || hh >= H_) continue;
                unsigned r = (unsigned)(b * PLANE + dd * HW_ + hh * W_);
                int j = kd * 9 + kh * 3;
                const unsigned short* p0 = T + (size_t)j * NVOX + r;
                const unsigned short* p1 = p0 + NVOX;
                const unsigned short* p2 = p1 + NVOX;
                uint4 A0 = *(const uint4*)(p0 + w0);
                uint4 A1 = *(const uint4*)(p1 + w0);
                uint4 A2 = *(const uint4*)(p2 + w0);
                float eL = (w0 > 0) ? bflo((unsigned)p0[w0 - 1]) : 0.f;
                float eR = (w0 + 8 < W_) ? bflo((unsigned)p2[w0 + 8]) : 0.f;
                unsigned x0[4] = {A0.x, A0.y, A0.z, A0.w};
                unsigned x1[4] = {A1.x, A1.y, A1.z, A1.w};
                unsigned x2[4] = {A2.x, A2.y, A2.z, A2.w};
                float a0[8], a1[8], a2[8];
#pragma unroll
                for (int k = 0; k < 4; ++k) {
                    a0[2 * k] = bflo(x0[k]); a0[2 * k + 1] = bfhi(x0[k]);
                    a1[2 * k] = bflo(x1[k]); a1[2 * k + 1] = bfhi(x1[k]);
                    a2[2 * k] = bflo(x2[k]); a2[2 * k + 1] = bfhi(x2[k]);
                }
                acc[0] += eL + a1[0] + a2[1];
#pragma unroll
                for (int i = 1; i < 7; ++i) acc[i] += a0[i - 1] + a1[i] + a2[i + 1];
                acc[7] += a0[6] + a1[7] + eR;
            }
        }
#pragma unroll
        for (int i = 0; i < 8; ++i) lc[d][o * 8 + i] = acc[i];
    }
    __syncthreads();

    // ---- phase 2: per-pixel softmax with 6-way depth parallelism ----
    const int l = tid & 63;                    // pixel within chunk
    const int g = tid / 64;                    // depth sixth: d in [g*8, g*8+8)
    const int pixg = pix0 + l;
    const int b = pixg / HW_;
    const int pp = pixg - b * HW_;

    float p[8];
    float mx = -1e30f;
#pragma unroll
    for (int i = 0; i < 8; ++i) {
        p[i] = lc[g * 8 + i][l];
        mx = fmaxf(mx, p[i]);
    }
    red[g][l] = mx;
    __syncthreads();
    mx = red[0][l];
#pragma unroll
    for (int k = 1; k < 6; ++k) mx = fmaxf(mx, red[k][l]);
    float S = 0.f;
#pragma unroll
    for (int i = 0; i < 8; ++i) {
        p[i] = expf(p[i] - mx);
        S += p[i];
    }
    __syncthreads();
    red[g][l] = S;
    __syncthreads();
    S = red[0][l] + red[1][l] + red[2][l] + red[3][l] + red[4][l] + red[5][l];
    float invS = 1.f / S;
    float S2p = 0.f;
#pragma unroll
    for (int i = 0; i < 8; ++i) {
        p[i] *= invS;             // prob
        S2p += p[i];
    }
    __syncthreads();
    red[g][l] = S2p;
    __syncthreads();
    float S2 = red[0][l] + red[1][l] + red[2][l] + red[3][l] + red[4][l] + red[5][l];
    float invS2 = 1.f / fmaxf(S2, 1e-12f);
    float dp = 0.f, difp = 0.f;
#pragma unroll
    for (int i = 0; i < 8; ++i) {
        int d0 = g * 8 + i;
        dp = fmaf(p[i] * invS2, dv[b * D_ + d0], dp);
        difp = fmaf(p[i], (float)d0, difp);
    }
    __syncthreads();
    red[g][l] = dp;
    __syncthreads();
    float depth = red[0][l] + red[1][l] + red[2][l] + red[3][l] + red[4][l] + red[5][l];
    __syncthreads();
    red[g][l] = difp;
    __syncthreads();
    float dif = red[0][l] + red[1][l] + red[2][l] + red[3][l] + red[4][l] + red[5][l];
    int di = (int)dif;
    di = min(max(di, 0), D_ - 1);
    float cf = 0.f;
#pragma unroll
    for (int i = 0; i < 8; ++i) {
        int d0 = g * 8 + i;
        if (d0 >= di - 1 && d0 <= di + 2) cf += p[i];
    }
    __syncthreads();
    red[g][l] = cf;
    __syncthreads();
    float conf = red[0][l] + red[1][l] + red[2][l] + red[3][l] + red[4][l] + red[5][l];

    if (g == 0) {
        out[pixg] = depth;
        out[B_ * HW_ + pixg] = conf;
    }
    float* itg = out + 2 * B_ * HW_ + (size_t)b * PLANE + pp;
#pragma unroll
    for (int i = 0; i < 8; ++i)
        itg[(size_t)(g * 8 + i) * HW_] = p[i] * invS2;
}

extern "C" void kernel_launch(void* const* d_in, const int* in_sizes, int n_in,
                              void* d_out, int out_size, void* d_ws, size_t ws_size,
                              hipStream_t stream) {
    const float* feat = (const float*)d_in[0];   // (B,V,C,H,W)
    const float* proj = (const float*)d_in[1];   // (B,V,2,4,4)
    const float* dv   = (const float*)d_in[2];   // (B,D)
    const float* wreg = (const float*)d_in[3];   // (1,C,3,3,3)
    float* out = (float*)d_out;
    float* ws = (float*)d_ws;

    // workspace layout (floats)
    const size_t rt_off = 0;
    const size_t rt_sz = 128;
    const size_t wtb_off = rt_off + rt_sz;
    const size_t wtb_sz = 512;                            // 2*64*4 uints
    const size_t fcl_off = wtb_off + wtb_sz;
    const size_t fcl_sz = (size_t)B_ * V_ * HW_ * 16;     // bf16 pixels: 16 uints each
    const size_t T_off = fcl_off + fcl_sz;
    const size_t T_sz = (size_t)27 * NVOX / 2;            // bf16 taps (float-slots)
    const size_t need = (T_off + T_sz) * sizeof(float);
    if (ws_size < need) return;  // workspace too small — fail loudly

    float* rt = ws + rt_off;
    unsigned* wtb = (unsigned*)(ws + wtb_off);
    unsigned* feat_cl = (unsigned*)(ws + fcl_off);
    unsigned short* T = (unsigned short*)(ws + T_off);

    setup_kernel<<<1, 128, 0, stream>>>(proj, wreg, rt, wtb);
    transpose_kernel<<<(B_ * V_ * HW_) / 256, 256, 0, stream>>>(feat, feat_cl);
    dim3 wgrid(HW_ / 64, D_, B_);
    warp_kernel<<<wgrid, 256, 0, stream>>>((const unsigned char*)feat_cl, rt, dv, wtb, T);
    costout_kernel<<<(B_ * HW_) / 64, 384, 0, stream>>>(T, dv, out);
}

// Round 15
// 201.493 us; speedup vs baseline: 1.1001x; 1.1001x over previous
//
#include <hip/hip_runtime.h>
#include <math.h>

// Problem constants (from setup_inputs): B,V,C,D,H,W = 2,5,32,48,128,160
constexpr int B_ = 2;
constexpr int V_ = 5;
constexpr int C_ = 32;
constexpr int D_ = 48;
constexpr int H_ = 128;
constexpr int W_ = 160;
constexpr int HW_ = H_ * W_;               // 20480
constexpr int NVOX = B_ * D_ * HW_;        // 1,966,080
constexpr int PLANE = D_ * HW_;            // 983,040 (per-batch voxels)

typedef _Float16 half2_t __attribute__((ext_vector_type(2)));
typedef _Float16 half8_t __attribute__((ext_vector_type(8)));
typedef float floatx4 __attribute__((ext_vector_type(4)));

// v_perm_b32 selectors: result = (u0.half_k, u1.half_k) as half2 (u0 in low)
constexpr unsigned SEL_LO = 0x01000504u;   // bytes: u0.b0,u0.b1,u1.b0,u1.b1
constexpr unsigned SEL_HI = 0x03020706u;   // bytes: u0.b2,u0.b3,u1.b2,u1.b3

// ---------------- small matrix helpers (device) ----------------

__device__ inline void combine4(const float* pm, float out[4][4]) {
    const float* E = pm;
    const float* K = pm + 16;
    for (int i = 0; i < 3; ++i)
        for (int j = 0; j < 4; ++j) {
            float a = 0.f;
            for (int k = 0; k < 3; ++k) a += K[i * 4 + k] * E[k * 4 + j];
            out[i][j] = a;
        }
    for (int j = 0; j < 4; ++j) out[3][j] = E[12 + j];
}

__device__ inline void invert4(const float A[4][4], float inv[4][4]) {
    float M[4][8];
    for (int i = 0; i < 4; ++i)
        for (int j = 0; j < 4; ++j) {
            M[i][j] = A[i][j];
            M[i][4 + j] = (i == j) ? 1.f : 0.f;
        }
    for (int col = 0; col < 4; ++col) {
        int piv = col;
        float best = fabsf(M[col][col]);
        for (int r = col + 1; r < 4; ++r) {
            float v = fabsf(M[r][col]);
            if (v > best) { best = v; piv = r; }
        }
        if (piv != col)
            for (int j = 0; j < 8; ++j) { float t = M[col][j]; M[col][j] = M[piv][j]; M[piv][j] = t; }
        float ip = 1.f / M[col][col];
        for (int j = 0; j < 8; ++j) M[col][j] *= ip;
        for (int r = 0; r < 4; ++r) {
            if (r == col) continue;
            float f = M[r][col];
            for (int j = 0; j < 8; ++j) M[r][j] -= f * M[col][j];
        }
    }
    for (int i = 0; i < 4; ++i)
        for (int j = 0; j < 4; ++j) inv[i][j] = M[i][4 + j];
}

__device__ inline unsigned bf_rne(float f) {
    unsigned u = __float_as_uint(f);
    return (u + 0x7FFFu + ((u >> 16) & 1u)) >> 16;   // RNE (values are finite)
}

__device__ inline float bflo(unsigned u) { return __uint_as_float(u << 16); }
__device__ inline float bfhi(unsigned u) { return __uint_as_float(u & 0xffff0000u); }

__device__ inline unsigned h2pack(float a, float b) {   // fp16 RNE pair
    unsigned lo = (unsigned)__builtin_bit_cast(unsigned short, (_Float16)a);
    unsigned hi = (unsigned)__builtin_bit_cast(unsigned short, (_Float16)b);
    return lo | (hi << 16);
}

// setup: (a) per b,v: P = src_proj @ inv(ref_proj) -> rt[12 floats]
//        (b) prepack conv weights as fp16 MFMA A-fragments:
//            A[m=tap=lane&15 (+16i)][k=ch=(lane>>4)*8+j], taps>=27 zero-padded
__global__ void setup_kernel(const float* __restrict__ proj, const float* __restrict__ wreg,
                             float* __restrict__ rt, unsigned* __restrict__ wtb) {
    int t = threadIdx.x;
    if (t < B_) {
        int b = t;
        float ref[4][4], inv[4][4];
        combine4(proj + (size_t)((b * V_ + 0) * 2) * 16, ref);
        invert4(ref, inv);
        for (int v = 1; v < V_; ++v) {
            float src[4][4];
            combine4(proj + (size_t)((b * V_ + v) * 2) * 16, src);
            float P[3][4];
            for (int i = 0; i < 3; ++i)
                for (int j = 0; j < 4; ++j) {
                    float a = 0.f;
                    for (int k = 0; k < 4; ++k) a += src[i][k] * inv[k][j];
                    P[i][j] = a;
                }
            float* o = rt + (size_t)(b * (V_ - 1) + (v - 1)) * 12;
            o[0] = P[0][0]; o[1] = P[0][1]; o[2] = P[0][2];
            o[3] = P[1][0]; o[4] = P[1][1]; o[5] = P[1][2];
            o[6] = P[2][0]; o[7] = P[2][1]; o[8] = P[2][2];
            o[9] = P[0][3]; o[10] = P[1][3]; o[11] = P[2][3];
        }
    }
    if (t < 128) {
        int i = t >> 6;          // which mfma (taps 0-15 / 16-31)
        int lane = t & 63;
        int q = lane >> 4;
        int l = lane & 15;
        int tap = i * 16 + l;
        unsigned u[4];
#pragma unroll
        for (int jj = 0; jj < 4; ++jj) {
            int ch0 = q * 8 + 2 * jj;
            float v0 = (tap < 27) ? wreg[ch0 * 27 + tap] : 0.f;
            float v1 = (tap < 27) ? wreg[(ch0 + 1) * 27 + tap] : 0.f;
            u[jj] = h2pack(v0, v1);
        }
        uint4* o = (uint4*)wtb;
        o[i * 64 + lane] = make_uint4(u[0], u[1], u[2], u[3]);
    }
}

// transpose features (B,V,C,H,W) f32 -> channel-last fp16 (B,V,H,W,C): 64 B/pixel
__global__ __launch_bounds__(256) void transpose_kernel(const float* __restrict__ feat,
                                                        unsigned* __restrict__ feat_cl) {
    int idx = blockIdx.x * 256 + threadIdx.x;  // over B*V*HW
    if (idx >= B_ * V_ * HW_) return;
    int pix = idx % HW_;
    int bv = idx / HW_;
    const float* src = feat + (size_t)bv * C_ * HW_ + pix;
    unsigned u[16];
#pragma unroll
    for (int j = 0; j < 16; ++j)
        u[j] = h2pack(src[(size_t)(2 * j) * HW_], src[(size_t)(2 * j + 1) * HW_]);
    uint4* dst = (uint4*)(feat_cl + (size_t)idx * 16);
    dst[0] = make_uint4(u[0], u[1], u[2], u[3]);
    dst[1] = make_uint4(u[4], u[5], u[6], u[7]);
    dst[2] = make_uint4(u[8], u[9], u[10], u[11]);
    dst[3] = make_uint4(u[12], u[13], u[14], u[15]);
}

// Fused homography warp + bilinear + variance + conv channel-reduction.
// Block = 256 threads = 64 pixels x 4 channel-quarter lanes; grid (320, D, B).
// fp16 channel-last features: one 16B load = a corner's 8 channels. Bilinear
// runs on packed math: v_perm_b32 pairs (corner00,corner01) channel values,
// v_dot2_f32_f16 does 2 MACs/slot against fp16-packed weights (fp16 has MORE
// mantissa than the previous bf16 path). Lane cq of each quad computes view
// cq's projection; packed weights (2 shfls) + offsets broadcast per view.
// T-dot on f16 MFMA (same rate/layout as bf16); 27 tap planes stored as bf16.
// T layout: [j=0..26][b][d][h][w], ushort.
__global__ __launch_bounds__(256) void warp_kernel(const unsigned char* __restrict__ fb,
                                                   const float* __restrict__ rt,
                                                   const float* __restrict__ dv,
                                                   const unsigned* __restrict__ wtb,
                                                   unsigned short* __restrict__ T) {
    const int tid = threadIdx.x;
    const int lane = tid & 63;
    const int cq = tid & 3;                   // channel quarter
    const int b = blockIdx.z;
    const int d = blockIdx.y;
    const int pixb = blockIdx.x * 64;         // block's first pixel
    const int pix = pixb + (tid >> 2);
    const int w = pix % W_;
    const int h = pix / W_;
    const float wf = (float)w, hf = (float)h;
    const float dep = dv[b * D_ + d];         // uniform -> s_load

    // A-fragments (fp16 conv weights), constant per lane
    const uint4* wp = (const uint4*)wtb;
    uint4 a0u = wp[lane];
    uint4 a1u = wp[64 + lane];

    // own view (cq): projection + packed bilinear weights + corner pixel indices
    unsigned wABu, wGDu;                      // half2 (w00,w01), (w10,w11)
    int pix00, pix01, pix10, pix11;
    {
        const float* m = rt + (b * (V_ - 1) + cq) * 12;
        float xp = fmaf(fmaf(m[0], wf, fmaf(m[1], hf, m[2])), dep, m[9]);
        float yp = fmaf(fmaf(m[3], wf, fmaf(m[4], hf, m[5])), dep, m[10]);
        float zp = fmaf(fmaf(m[6], wf, fmaf(m[7], hf, m[8])), dep, m[11]);
        float iz = __builtin_amdgcn_rcpf(zp);
        float ix = xp * iz, iy = yp * iz;
        float x0f = floorf(ix), y0f = floorf(iy);
        float wx1 = ix - x0f, wx0 = 1.f - wx1;
        float wy1 = iy - y0f, wy0 = 1.f - wy1;
        float x1f = x0f + 1.f, y1f = y0f + 1.f;
        bool vx0 = (x0f >= 0.f) && (x0f <= (float)(W_ - 1));
        bool vx1 = (x1f >= 0.f) && (x1f <= (float)(W_ - 1));
        bool vy0 = (y0f >= 0.f) && (y0f <= (float)(H_ - 1));
        bool vy1 = (y1f >= 0.f) && (y1f <= (float)(H_ - 1));
        int x0i = (int)fminf(fmaxf(x0f, 0.f), (float)(W_ - 1));
        int x1i = (int)fminf(fmaxf(x1f, 0.f), (float)(W_ - 1));
        int y0i = (int)fminf(fmaxf(y0f, 0.f), (float)(H_ - 1));
        int y1i = (int)fminf(fmaxf(y1f, 0.f), (float)(H_ - 1));
        float w00 = wx0 * wy0 * ((vx0 && vy0) ? 1.f : 0.f);
        float w01 = wx1 * wy0 * ((vx1 && vy0) ? 1.f : 0.f);
        float w10 = wx0 * wy1 * ((vx0 && vy1) ? 1.f : 0.f);
        float w11 = wx1 * wy1 * ((vx1 && vy1) ? 1.f : 0.f);
        wABu = __builtin_bit_cast(unsigned, __builtin_amdgcn_cvt_pkrtz(w00, w01));
        wGDu = __builtin_bit_cast(unsigned, __builtin_amdgcn_cvt_pkrtz(w10, w11));
        pix00 = y0i * W_ + x0i;
        pix01 = y0i * W_ + x1i;
        pix10 = y1i * W_ + x0i;
        pix11 = y1i * W_ + x1i;
    }

    // ref view: own pixel, own 8 channels (fp16x8 = one 16B load)
    float s[8], q[8];
    {
        const unsigned char* rb = fb + (size_t)(b * V_) * HW_ * 64;
        uint4 r = *(const uint4*)(rb + (((unsigned)pix) << 6) + (cq << 4));
        half8_t rf = __builtin_bit_cast(half8_t, r);
#pragma unroll
        for (int j = 0; j < 8; ++j) {
            float f = (float)rf[j];
            s[j] = f;
            q[j] = f * f;
        }
    }

#pragma unroll
    for (int v = 0; v < V_ - 1; ++v) {
        int sl = (lane & ~3) | v;             // quad-local broadcast source
        half2_t WA = __builtin_bit_cast(half2_t, (unsigned)__shfl((int)wABu, sl));
        half2_t WB = __builtin_bit_cast(half2_t, (unsigned)__shfl((int)wGDu, sl));
        unsigned O00 = ((unsigned)__shfl(pix00, sl) << 6) + (cq << 4);
        unsigned O01 = ((unsigned)__shfl(pix01, sl) << 6) + (cq << 4);
        unsigned O10 = ((unsigned)__shfl(pix10, sl) << 6) + (cq << 4);
        unsigned O11 = ((unsigned)__shfl(pix11, sl) << 6) + (cq << 4);
        const unsigned char* base = fb + (size_t)(b * V_ + v + 1) * HW_ * 64;
        uint4 c0 = *(const uint4*)(base + O00);
        uint4 c1 = *(const uint4*)(base + O01);
        uint4 c2 = *(const uint4*)(base + O10);
        uint4 c3 = *(const uint4*)(base + O11);
        unsigned u0[4] = {c0.x, c0.y, c0.z, c0.w};
        unsigned u1[4] = {c1.x, c1.y, c1.z, c1.w};
        unsigned u2[4] = {c2.x, c2.y, c2.z, c2.w};
        unsigned u3[4] = {c3.x, c3.y, c3.z, c3.w};
#pragma unroll
        for (int jj = 0; jj < 4; ++jj) {
            // channel 2jj (low halves)
            unsigned ab = __builtin_amdgcn_perm(u0[jj], u1[jj], SEL_LO);
            unsigned gd = __builtin_amdgcn_perm(u2[jj], u3[jj], SEL_LO);
            float acc = __builtin_amdgcn_fdot2(
                __builtin_bit_cast(half2_t, ab), WA,
                __builtin_amdgcn_fdot2(__builtin_bit_cast(half2_t, gd), WB, 0.f, false),
                false);
            s[2 * jj] += acc;
            q[2 * jj] = fmaf(acc, acc, q[2 * jj]);
            // channel 2jj+1 (high halves)
            unsigned ab1 = __builtin_amdgcn_perm(u0[jj], u1[jj], SEL_HI);
            unsigned gd1 = __builtin_amdgcn_perm(u2[jj], u3[jj], SEL_HI);
            float acc1 = __builtin_amdgcn_fdot2(
                __builtin_bit_cast(half2_t, ab1), WA,
                __builtin_amdgcn_fdot2(__builtin_bit_cast(half2_t, gd1), WB, 0.f, false),
                false);
            s[2 * jj + 1] += acc1;
            q[2 * jj + 1] = fmaf(acc1, acc1, q[2 * jj + 1]);
        }
    }

    // variance for this thread's 8 channels, packed to fp16 (1 op per pair)
    const float invV = 1.0f / (float)V_;
    unsigned pk[4];
#pragma unroll
    for (int jj = 0; jj < 4; ++jj) {
        float m0 = s[2 * jj] * invV, m1 = s[2 * jj + 1] * invV;
        float v0 = fmaf(-m0, m0, q[2 * jj] * invV);
        float v1 = fmaf(-m1, m1, q[2 * jj + 1] * invV);
        pk[jj] = __builtin_bit_cast(unsigned, __builtin_amdgcn_cvt_pkrtz(v0, v1));
    }

    // permute to B-fragment layout: target lane L gets (voxel L&15, quarter L>>4)
    // which lives in source lane (L&15)*4 + (L>>4)
    uint4 bu;
    {
        int srcl = ((lane & 15) << 2) + (lane >> 4);
        bu.x = (unsigned)__shfl((int)pk[0], srcl);
        bu.y = (unsigned)__shfl((int)pk[1], srcl);
        bu.z = (unsigned)__shfl((int)pk[2], srcl);
        bu.w = (unsigned)__shfl((int)pk[3], srcl);
    }
    half8_t bfrag = __builtin_bit_cast(half8_t, bu);
    half8_t afrag0 = __builtin_bit_cast(half8_t, a0u);
    half8_t afrag1 = __builtin_bit_cast(half8_t, a1u);

    floatx4 z = {0.f, 0.f, 0.f, 0.f};
    // D[m=tap][n=voxel-in-wave]; lane L: col=L&15, rows=(L>>4)*4+r
    floatx4 t0 = __builtin_amdgcn_mfma_f32_16x16x32_f16(afrag0, bfrag, z, 0, 0, 0);
    floatx4 t1 = __builtin_amdgcn_mfma_f32_16x16x32_f16(afrag1, bfrag, z, 0, 0, 0);

    // store taps as bf16 straight to the 27 T planes
    const unsigned gidx = (unsigned)(b * PLANE + d * HW_ + pixb + ((tid >> 6) << 4) + (lane & 15));
    const int tq = (lane >> 4) << 2;
#pragma unroll
    for (int r = 0; r < 4; ++r) {
        T[(unsigned)((tq + r) * NVOX) + gidx] = (unsigned short)bf_rne(t0[r]);
        int tap2 = 16 + tq + r;
        if (tap2 < 27) T[(unsigned)(tap2 * NVOX) + gidx] = (unsigned short)bf_rne(t1[r]);
    }
}

// Vectorized cost: thread = 8 consecutive w-voxels (aligned; 8 | W). Per
// (kd,kh): 3 aligned uint4 loads (8 bf16 taps) + 2 predicated scalar edge
// loads; kw handled by register shifts.
__global__ __launch_bounds__(256) void cost_kernel(const unsigned short* __restrict__ T,
                                                   float* __restrict__ cost) {
    int t = blockIdx.x * 256 + threadIdx.x;    // over NVOX/8
    int v0 = t * 8;
    int w0 = v0 % W_;
    int h = (v0 / W_) % H_;
    int d = (v0 / HW_) % D_;
    int b = v0 / PLANE;
    float acc[8];
#pragma unroll
    for (int i = 0; i < 8; ++i) acc[i] = 0.f;

#pragma unroll
    for (int kd = 0; kd < 3; ++kd) {
        int dd = d + kd - 1;
        if (dd < 0 || dd >= D_) continue;
#pragma unroll
        for (int kh = 0; kh < 3; ++kh) {
            int hh = h + kh - 1;
            if (hh < 0 || hh >= H_) continue;
            unsigned r = (unsigned)(b * PLANE + dd * HW_ + hh * W_);
            int j = kd * 9 + kh * 3;
            const unsigned short* p0 = T + (size_t)j * NVOX + r;
            const unsigned short* p1 = p0 + NVOX;
            const unsigned short* p2 = p1 + NVOX;
            uint4 A0 = *(const uint4*)(p0 + w0);
            uint4 A1 = *(const uint4*)(p1 + w0);
            uint4 A2 = *(const uint4*)(p2 + w0);
            float eL = (w0 > 0) ? bflo((unsigned)p0[w0 - 1]) : 0.f;
            float eR = (w0 + 8 < W_) ? bflo((unsigned)p2[w0 + 8]) : 0.f;
            unsigned x0[4] = {A0.x, A0.y, A0.z, A0.w};
            unsigned x1[4] = {A1.x, A1.y, A1.z, A1.w};
            unsigned x2[4] = {A2.x, A2.y, A2.z, A2.w};
            float a0[8], a1[8], a2[8];
#pragma unroll
            for (int k = 0; k < 4; ++k) {
                a0[2 * k] = bflo(x0[k]); a0[2 * k + 1] = bfhi(x0[k]);
                a1[2 * k] = bflo(x1[k]); a1[2 * k + 1] = bfhi(x1[k]);
                a2[2 * k] = bflo(x2[k]); a2[2 * k + 1] = bfhi(x2[k]);
            }
            acc[0] += eL + a1[0] + a2[1];
#pragma unroll
            for (int i = 1; i < 7; ++i) acc[i] += a0[i - 1] + a1[i] + a2[i + 1];
            acc[7] += a0[6] + a1[7] + eR;
        }
    }
    float4* cp = (float4*)(cost + v0);
    cp[0] = make_float4(acc[0], acc[1], acc[2], acc[3]);
    cp[1] = make_float4(acc[4], acc[5], acc[6], acc[7]);
}

// Parallel softmax/depth/conf/itg: block = 64 pixels x 4 depth-quarters.
__global__ __launch_bounds__(256) void out_kernel(const float* __restrict__ cost,
                                                  const float* __restrict__ dv,
                                                  float* __restrict__ out) {
    __shared__ float red[4][64];
    const int tid = threadIdx.x;
    const int lane = tid & 63;
    const int wq = tid >> 6;                  // depth quarter
    const int pixg = blockIdx.x * 64 + lane;  // over B*HW
    const int b = pixg / HW_;
    const int pix = pixg - b * HW_;
    const float* cb = cost + (size_t)b * PLANE + pix;

    float p[12];
    float mx = -1e30f;
#pragma unroll
    for (int i = 0; i < 12; ++i) {
        p[i] = cb[(size_t)(wq * 12 + i) * HW_];
        mx = fmaxf(mx, p[i]);
    }
    red[wq][lane] = mx;
    __syncthreads();
    mx = fmaxf(fmaxf(red[0][lane], red[1][lane]), fmaxf(red[2][lane], red[3][lane]));
    float S = 0.f;
#pragma unroll
    for (int i = 0; i < 12; ++i) {
        p[i] = expf(p[i] - mx);
        S += p[i];
    }
    __syncthreads();
    red[wq][lane] = S;
    __syncthreads();
    S = red[0][lane] + red[1][lane] + red[2][lane] + red[3][lane];
    float invS = 1.f / S;
    float S2p = 0.f;
#pragma unroll
    for (int i = 0; i < 12; ++i) {
        p[i] *= invS;             // prob
        S2p += p[i];
    }
    __syncthreads();
    red[wq][lane] = S2p;
    __syncthreads();
    float S2 = red[0][lane] + red[1][lane] + red[2][lane] + red[3][lane];
    float invS2 = 1.f / fmaxf(S2, 1e-12f);
    float dp = 0.f, difp = 0.f;
#pragma unroll
    for (int i = 0; i < 12; ++i) {
        int d0 = wq * 12 + i;
        dp = fmaf(p[i] * invS2, dv[b * D_ + d0], dp);
        difp = fmaf(p[i], (float)d0, difp);
    }
    __syncthreads();
    red[wq][lane] = dp;
    __syncthreads();
    float depth = red[0][lane] + red[1][lane] + red[2][lane] + red[3][lane];
    __syncthreads();
    red[wq][lane] = difp;
    __syncthreads();
    float dif = red[0][lane] + red[1][lane] + red[2][lane] + red[3][lane];
    int di = (int)dif;
    di = min(max(di, 0), D_ - 1);
    float cf = 0.f;
#pragma unroll
    for (int i = 0; i < 12; ++i) {
        int d0 = wq * 12 + i;
        if (d0 >= di - 1 && d0 <= di + 2) cf += p[i];
    }
    __syncthreads();
    red[wq][lane] = cf;
    __syncthreads();
    float conf = red[0][lane] + red[1][lane] + red[2][lane] + red[3][lane];

    if (wq == 0) {
        out[pixg] = depth;
        out[B_ * HW_ + pixg] = conf;
    }
    float* itg = out + 2 * B_ * HW_ + (size_t)b * PLANE + pix;
#pragma unroll
    for (int i = 0; i < 12; ++i)
        itg[(size_t)(wq * 12 + i) * HW_] = p[i] * invS2;
}

extern "C" void kernel_launch(void* const* d_in, const int* in_sizes, int n_in,
                              void* d_out, int out_size, void* d_ws, size_t ws_size,
                              hipStream_t stream) {
    const float* feat = (const float*)d_in[0];   // (B,V,C,H,W)
    const float* proj = (const float*)d_in[1];   // (B,V,2,4,4)
    const float* dv   = (const float*)d_in[2];   // (B,D)
    const float* wreg = (const float*)d_in[3];   // (1,C,3,3,3)
    float* out = (float*)d_out;
    float* ws = (float*)d_ws;

    // workspace layout (floats)
    const size_t rt_off = 0;
    const size_t rt_sz = 128;
    const size_t wtb_off = rt_off + rt_sz;
    const size_t wtb_sz = 512;                            // 2*64*4 uints
    const size_t fcl_off = wtb_off + wtb_sz;
    const size_t fcl_sz = (size_t)B_ * V_ * HW_ * 16;     // fp16 pixels: 16 uints each
    const size_t T_off = fcl_off + fcl_sz;
    const size_t T_sz = (size_t)27 * NVOX / 2;            // bf16 taps (float-slots)
    const size_t cost_off = T_off + T_sz;
    const size_t cost_sz = (size_t)NVOX;
    const size_t need = (cost_off + cost_sz) * sizeof(float);
    if (ws_size < need) return;  // workspace too small — fail loudly

    float* rt = ws + rt_off;
    unsigned* wtb = (unsigned*)(ws + wtb_off);
    unsigned* feat_cl = (unsigned*)(ws + fcl_off);
    unsigned short* T = (unsigned short*)(ws + T_off);
    float* cost = ws + cost_off;

    setup_kernel<<<1, 128, 0, stream>>>(proj, wreg, rt, wtb);
    transpose_kernel<<<(B_ * V_ * HW_) / 256, 256, 0, stream>>>(feat, feat_cl);
    dim3 wgrid(HW_ / 64, D_, B_);
    warp_kernel<<<wgrid, 256, 0, stream>>>((const unsigned char*)feat_cl, rt, dv, wtb, T);
    cost_kernel<<<(NVOX / 8) / 256, 256, 0, stream>>>(T, cost);
    out_kernel<<<(B_ * HW_) / 64, 256, 0, stream>>>(cost, dv, out);
}